// Round 5
// baseline (87.253 us; speedup 1.0000x reference)
//
#include <hip/hip_runtime.h>
#include <hip/hip_bf16.h>

typedef short short8 __attribute__((ext_vector_type(8)));
typedef float f32x4  __attribute__((ext_vector_type(4)));

#define ND 128
#define LD 128
#define EE 128
#define NQ 128
#define LQ 32
#define LDS_STRIDE 136   // 128 + 8 bf16 pad: A-frag ds_read_b128 -> 2-way max (free)
#define LDSH (LD * LDS_STRIDE)

// ---- Kernel 1: merged convert.
// blocks [0, 2048): doc fp32 -> bf16 copy-cast (1 float4/thread)
// blocks [2048, 2176): query fp32 [E][Lq] -> bf16 [Lq][E] via LDS transpose ----
__global__ __launch_bounds__(256)
void convert_kernel(const float* __restrict__ doc, const float* __restrict__ qry,
                    __hip_bfloat16* __restrict__ docB, __hip_bfloat16* __restrict__ qB) {
  const int tid = threadIdx.x;
  if (blockIdx.x < 2048) {
    int gid = blockIdx.x * 256 + tid;        // 524288 float4 chunks of doc
    float4 v = reinterpret_cast<const float4*>(doc)[gid];
    union { ushort4 u; __hip_bfloat16 b[4]; } o;
    o.b[0] = __float2bfloat16(v.x);
    o.b[1] = __float2bfloat16(v.y);
    o.b[2] = __float2bfloat16(v.z);
    o.b[3] = __float2bfloat16(v.w);
    reinterpret_cast<ushort4*>(docB)[gid] = o.u;
    return;
  }
  __shared__ float s[LQ][EE + 1];            // 32 x 129 fp32
  const int q = blockIdx.x - 2048;
  const float* src = qry + q * (EE * LQ);
  #pragma unroll
  for (int i = 0; i < 4; ++i) {              // coalesced float4 read of [E][L]
    int c = i * 256 + tid;
    int e = c >> 3;
    int l = (c & 7) << 2;
    float4 v = reinterpret_cast<const float4*>(src)[c];
    s[l + 0][e] = v.x;
    s[l + 1][e] = v.y;
    s[l + 2][e] = v.z;
    s[l + 3][e] = v.w;
  }
  __syncthreads();
  __hip_bfloat16* dst = qB + q * (LQ * EE);
  #pragma unroll
  for (int i = 0; i < 4; ++i) {              // coalesced ushort4 write of [L][E]
    int c = i * 256 + tid;
    int l = c >> 5;
    int e = (c & 31) << 2;
    union { ushort4 u; __hip_bfloat16 b[4]; } o;
    o.b[0] = __float2bfloat16(s[l][e + 0]);
    o.b[1] = __float2bfloat16(s[l][e + 1]);
    o.b[2] = __float2bfloat16(s[l][e + 2]);
    o.b[3] = __float2bfloat16(s[l][e + 3]);
    reinterpret_cast<ushort4*>(dst)[c] = o.u;
  }
}

// ---- Kernel 2: fused maxsim, query-resident + double-buffered doc staging.
// Block = 512 threads (8 waves) = (2 docs, 16 queries). Grid 64x8 = 512 blocks
// = exactly 2 blocks/CU co-resident (LDS 2*34816*2 = 136KB <= 160KB).
// Wave holds its 2 queries' B-frags (64 VGPRs) the whole kernel. Doc g+1 is
// prefetched into 16 VGPRs (4 uint4/thread) BEFORE computing doc g, then
// ds_written to the other LDS buffer — staging latency hides under ~10k cyc
// of MFMA. One barrier per doc. No min-waves bound (R2: forcing 128-reg
// budget spilled bfrag -> 200MB scratch traffic). ----
__global__ __launch_bounds__(512)
void maxsim_kernel(const __hip_bfloat16* __restrict__ docB,
                   const __hip_bfloat16* __restrict__ qB,
                   float* __restrict__ out) {
  __shared__ __hip_bfloat16 sdoc[2][LDSH];
  const int d0   = blockIdx.x * 2;
  const int qblk = blockIdx.y;
  const int tid  = threadIdx.x;
  const int wave = tid >> 6;
  const int lane = tid & 63;
  const int ln15 = lane & 15;        // m (A) / n (B) index within 16-tile
  const int quad = lane >> 4;        // k-group: k = quad*8 + j
  const int q0   = qblk * 16 + wave * 2;

  // B fragments: 2 queries x 2 n-tiles x 4 k-steps — loaded ONCE, held in regs.
  short8 bfrag[2][2][4];
  #pragma unroll
  for (int qq = 0; qq < 2; ++qq) {
    const __hip_bfloat16* qp = qB + (q0 + qq) * (LQ * EE);
    #pragma unroll
    for (int nt = 0; nt < 2; ++nt)
      #pragma unroll
      for (int ks = 0; ks < 4; ++ks)
        bfrag[qq][nt][ks] = *reinterpret_cast<const short8*>(
            qp + (nt * 16 + ln15) * EE + ks * 32 + quad * 8);
  }

  // Stage doc d0 into buffer 0: 2048 uint4 chunks, 4 per thread.
  uint4 pf[4];
  {
    const uint4* src = reinterpret_cast<const uint4*>(docB + d0 * (LD * EE));
    #pragma unroll
    for (int it = 0; it < 4; ++it) pf[it] = src[it * 512 + tid];
    #pragma unroll
    for (int it = 0; it < 4; ++it) {
      int idx = it * 512 + tid;      // 16 chunks (of 8 bf16) per row
      *reinterpret_cast<uint4*>(
          &sdoc[0][(idx >> 4) * LDS_STRIDE + ((idx & 15) << 3)]) = pf[it];
    }
  }
  __syncthreads();

  #pragma unroll 1
  for (int g = 0; g < 2; ++g) {
    if (g == 0) {
      // Prefetch doc d0+1 into regs BEFORE computing doc d0 (latency hides
      // under the MFMA loop; vmcnt wait lands at the ds_write below).
      const uint4* src = reinterpret_cast<const uint4*>(docB + (d0 + 1) * (LD * EE));
      #pragma unroll
      for (int it = 0; it < 4; ++it) pf[it] = src[it * 512 + tid];
    }

    // Scalar running max per (query, n-tile).
    float colmax[2][2] = {{-3.0e38f, -3.0e38f}, {-3.0e38f, -3.0e38f}};

    #pragma unroll
    for (int mt = 0; mt < 8; ++mt) {
      f32x4 acc[2][2];
      #pragma unroll
      for (int qq = 0; qq < 2; ++qq)
        #pragma unroll
        for (int nt = 0; nt < 2; ++nt)
          acc[qq][nt] = (f32x4){0.f, 0.f, 0.f, 0.f};

      #pragma unroll
      for (int ks = 0; ks < 4; ++ks) {
        short8 a = *reinterpret_cast<const short8*>(
            &sdoc[g][(mt * 16 + ln15) * LDS_STRIDE + ks * 32 + quad * 8]);
        acc[0][0] = __builtin_amdgcn_mfma_f32_16x16x32_bf16(a, bfrag[0][0][ks], acc[0][0], 0, 0, 0);
        acc[0][1] = __builtin_amdgcn_mfma_f32_16x16x32_bf16(a, bfrag[0][1][ks], acc[0][1], 0, 0, 0);
        acc[1][0] = __builtin_amdgcn_mfma_f32_16x16x32_bf16(a, bfrag[1][0][ks], acc[1][0], 0, 0, 0);
        acc[1][1] = __builtin_amdgcn_mfma_f32_16x16x32_bf16(a, bfrag[1][1][ks], acc[1][1], 0, 0, 0);
      }

      #pragma unroll
      for (int qq = 0; qq < 2; ++qq)
        #pragma unroll
        for (int nt = 0; nt < 2; ++nt)
          colmax[qq][nt] = fmaxf(colmax[qq][nt],
                                 fmaxf(fmaxf(acc[qq][nt][0], acc[qq][nt][1]),
                                       fmaxf(acc[qq][nt][2], acc[qq][nt][3])));
    }

    if (g == 0) {
      // Write prefetched doc d0+1 into buffer 1 (distinct buffer: no barrier
      // needed before the write; one barrier after, hidden behind epilogue).
      #pragma unroll
      for (int it = 0; it < 4; ++it) {
        int idx = it * 512 + tid;
        *reinterpret_cast<uint4*>(
            &sdoc[1][(idx >> 4) * LDS_STRIDE + ((idx & 15) << 3)]) = pf[it];
      }
    }

    // Epilogue: C/D layout col=lane&15, row=quad*4+reg. Max over row-groups
    // (shfl 16/32), sum over 32 cols (two tiles + shfl 1/2/4/8).
    #pragma unroll
    for (int qq = 0; qq < 2; ++qq) {
      float m0 = colmax[qq][0];
      float m1 = colmax[qq][1];
      m0 = fmaxf(m0, __shfl_xor(m0, 16, 64));
      m0 = fmaxf(m0, __shfl_xor(m0, 32, 64));
      m1 = fmaxf(m1, __shfl_xor(m1, 16, 64));
      m1 = fmaxf(m1, __shfl_xor(m1, 32, 64));
      float s = m0 + m1;
      s += __shfl_xor(s, 1, 64);
      s += __shfl_xor(s, 2, 64);
      s += __shfl_xor(s, 4, 64);
      s += __shfl_xor(s, 8, 64);
      if (lane == 0) out[(q0 + qq) * ND + d0 + g] = s;
    }

    if (g == 0) __syncthreads();
  }
}

extern "C" void kernel_launch(void* const* d_in, const int* in_sizes, int n_in,
                              void* d_out, int out_size, void* d_ws, size_t ws_size,
                              hipStream_t stream) {
  const float* doc = (const float*)d_in[0];   // [128,128,128] fp32
  const float* qry = (const float*)d_in[1];   // [128,128,32]  fp32
  float* out = (float*)d_out;                 // [128,128]     fp32

  __hip_bfloat16* docB = (__hip_bfloat16*)d_ws;            // 4 MiB
  __hip_bfloat16* qB   = docB + ND * LD * EE;              // 1 MiB

  convert_kernel<<<dim3(2048 + NQ), dim3(256), 0, stream>>>(doc, qry, docB, qB);
  maxsim_kernel<<<dim3(ND / 2, NQ / 16), dim3(512), 0, stream>>>(docB, qB, out);
}

// Round 6
// 81.379 us; speedup vs baseline: 1.0722x; 1.0722x over previous
//
#include <hip/hip_runtime.h>
#include <hip/hip_bf16.h>

typedef short short8 __attribute__((ext_vector_type(8)));
typedef float f32x16 __attribute__((ext_vector_type(16)));

#define ND 128
#define LD 128
#define EE 128
#define NQ 128
#define LQ 32
#define LDS_STRIDE 136   // 136 bf16 = 272 B/row = 17*16B (b128-aligned), breaks pow2 stride
#define GDOCS 2          // grid (64,16)=1024 blocks = 4/CU co-resident

// ---- Kernel 1: query fp32 [E][Lq] -> bf16 [Lq][E] via LDS transpose (128 blocks) ----
__global__ __launch_bounds__(256)
void qconvert_kernel(const float* __restrict__ qry, __hip_bfloat16* __restrict__ qB) {
  __shared__ float s[LQ][EE + 1];            // 32 x 129 fp32
  const int q   = blockIdx.x;
  const int tid = threadIdx.x;
  const float* src = qry + q * (EE * LQ);
  #pragma unroll
  for (int i = 0; i < 4; ++i) {              // coalesced float4 read of [E][L]
    int c = i * 256 + tid;
    int e = c >> 3;
    int l = (c & 7) << 2;
    float4 v = reinterpret_cast<const float4*>(src)[c];
    s[l + 0][e] = v.x;
    s[l + 1][e] = v.y;
    s[l + 2][e] = v.z;
    s[l + 3][e] = v.w;
  }
  __syncthreads();
  __hip_bfloat16* dst = qB + q * (LQ * EE);
  #pragma unroll
  for (int i = 0; i < 4; ++i) {              // coalesced ushort4 write of [L][E]
    int c = i * 256 + tid;
    int l = c >> 5;
    int e = (c & 31) << 2;
    union { ushort4 u; __hip_bfloat16 b[4]; } o;
    o.b[0] = __float2bfloat16(s[l][e + 0]);
    o.b[1] = __float2bfloat16(s[l][e + 1]);
    o.b[2] = __float2bfloat16(s[l][e + 2]);
    o.b[3] = __float2bfloat16(s[l][e + 3]);
    reinterpret_cast<ushort4*>(dst)[c] = o.u;
  }
}

// ---- Kernel 2: fused maxsim, 32x32x16 MFMA, query-resident, inline doc convert.
// Block = 256 threads (4 waves) = (2 docs serial, 8 queries). Grid 64x16 = 1024
// = 4 blocks/CU co-resident (LDS 34816*4 = 136KB <= 160KB; need VGPR <= 128).
// Wave holds 2 queries' B-frags (64 VGPRs) whole kernel. Doc staged from fp32
// with in-register cvt (no separate doc-convert dispatch).
// 32x32x16: 4060 FLOP/cyc vs 3378 for 16x16x32 (m119) -> 17% lower MFMA floor.
// No min-waves bound (R2: forcing 128-budget split 64/64 and spilled bfrag). ----
__global__ __launch_bounds__(256)
void maxsim_kernel(const float* __restrict__ doc,
                   const __hip_bfloat16* __restrict__ qB,
                   float* __restrict__ out) {
  __shared__ __hip_bfloat16 sdoc[LD * LDS_STRIDE];
  const int d0   = blockIdx.x * GDOCS;
  const int qblk = blockIdx.y;
  const int tid  = threadIdx.x;
  const int wave = tid >> 6;
  const int lane = tid & 63;
  const int ln31 = lane & 31;        // m (A rows) / n (B cols = query token l)
  const int half = lane >> 5;        // k-group: k = half*8 + j
  const int q0   = qblk * 8 + wave * 2;

  // B-frags, 32x32x16 layout: B[n=lane&31][k=ks*16+half*8+j]. 2 queries x 8 ks
  // = 64 VGPRs, loaded ONCE and held.
  short8 bfrag[2][8];
  #pragma unroll
  for (int qq = 0; qq < 2; ++qq) {
    const __hip_bfloat16* qp = qB + (q0 + qq) * (LQ * EE) + ln31 * EE + half * 8;
    #pragma unroll
    for (int ks = 0; ks < 8; ++ks)
      bfrag[qq][ks] = *reinterpret_cast<const short8*>(qp + ks * 16);
  }

  #pragma unroll 1
  for (int g = 0; g < GDOCS; ++g) {
    const int d = d0 + g;
    __syncthreads();   // g>0: sdoc still being read by other waves
    // Stage doc[d] fp32 -> bf16 LDS: 2048 out-chunks of 8 bf16, 8 per thread.
    // unroll 4 caps in-flight float4 loads (VGPR pressure: keep <= 128 total).
    {
      const float4* src = reinterpret_cast<const float4*>(doc + d * (LD * EE));
      #pragma unroll 4
      for (int it = 0; it < 8; ++it) {
        int c = it * 256 + tid;      // 16 chunks per 128-elem row
        float4 v0 = src[2 * c + 0];
        float4 v1 = src[2 * c + 1];
        union { uint4 u; __hip_bfloat16 b[8]; } o;
        o.b[0] = __float2bfloat16(v0.x);
        o.b[1] = __float2bfloat16(v0.y);
        o.b[2] = __float2bfloat16(v0.z);
        o.b[3] = __float2bfloat16(v0.w);
        o.b[4] = __float2bfloat16(v1.x);
        o.b[5] = __float2bfloat16(v1.y);
        o.b[6] = __float2bfloat16(v1.z);
        o.b[7] = __float2bfloat16(v1.w);
        *reinterpret_cast<uint4*>(&sdoc[(c >> 4) * LDS_STRIDE + ((c & 15) << 3)]) = o.u;
      }
    }
    __syncthreads();

    // Running per-column max (column = query token l = lane&31), per query.
    float colmax[2] = {-3.0e38f, -3.0e38f};

    #pragma unroll
    for (int mt = 0; mt < 4; ++mt) {       // 4 m-tiles of 32 doc tokens
      f32x16 acc0 = {0.f, 0.f, 0.f, 0.f, 0.f, 0.f, 0.f, 0.f,
                     0.f, 0.f, 0.f, 0.f, 0.f, 0.f, 0.f, 0.f};
      f32x16 acc1 = acc0;

      #pragma unroll
      for (int ks = 0; ks < 8; ++ks) {
        short8 a = *reinterpret_cast<const short8*>(
            &sdoc[(mt * 32 + ln31) * LDS_STRIDE + ks * 16 + half * 8]);
        acc0 = __builtin_amdgcn_mfma_f32_32x32x16_bf16(a, bfrag[0][ks], acc0, 0, 0, 0);
        acc1 = __builtin_amdgcn_mfma_f32_32x32x16_bf16(a, bfrag[1][ks], acc1, 0, 0, 0);
      }

      // Fold 16 rows/lane into running max (C/D: col=lane&31,
      // row=(reg&3)+8*(reg>>2)+4*half — 16 distinct rows per lane).
      float t0a = fmaxf(fmaxf(acc0[0], acc0[1]),  fmaxf(acc0[2], acc0[3]));
      float t0b = fmaxf(fmaxf(acc0[4], acc0[5]),  fmaxf(acc0[6], acc0[7]));
      float t0c = fmaxf(fmaxf(acc0[8], acc0[9]),  fmaxf(acc0[10], acc0[11]));
      float t0d = fmaxf(fmaxf(acc0[12], acc0[13]), fmaxf(acc0[14], acc0[15]));
      colmax[0] = fmaxf(colmax[0], fmaxf(fmaxf(t0a, t0b), fmaxf(t0c, t0d)));
      float t1a = fmaxf(fmaxf(acc1[0], acc1[1]),  fmaxf(acc1[2], acc1[3]));
      float t1b = fmaxf(fmaxf(acc1[4], acc1[5]),  fmaxf(acc1[6], acc1[7]));
      float t1c = fmaxf(fmaxf(acc1[8], acc1[9]),  fmaxf(acc1[10], acc1[11]));
      float t1d = fmaxf(fmaxf(acc1[12], acc1[13]), fmaxf(acc1[14], acc1[15]));
      colmax[1] = fmaxf(colmax[1], fmaxf(fmaxf(t1a, t1b), fmaxf(t1c, t1d)));
    }

    // Epilogue: combine the two k-halves' row groups (xor 32) -> per-column
    // max over all 128 doc tokens; sum the 32 columns (xor 1/2/4/8/16).
    #pragma unroll
    for (int qq = 0; qq < 2; ++qq) {
      float m = colmax[qq];
      m = fmaxf(m, __shfl_xor(m, 32, 64));
      float s = m;
      s += __shfl_xor(s, 1, 64);
      s += __shfl_xor(s, 2, 64);
      s += __shfl_xor(s, 4, 64);
      s += __shfl_xor(s, 8, 64);
      s += __shfl_xor(s, 16, 64);
      if (lane == 0) out[(q0 + qq) * ND + d] = s;
    }
  }
}

extern "C" void kernel_launch(void* const* d_in, const int* in_sizes, int n_in,
                              void* d_out, int out_size, void* d_ws, size_t ws_size,
                              hipStream_t stream) {
  const float* doc = (const float*)d_in[0];   // [128,128,128] fp32
  const float* qry = (const float*)d_in[1];   // [128,128,32]  fp32
  float* out = (float*)d_out;                 // [128,128]     fp32

  __hip_bfloat16* qB = (__hip_bfloat16*)d_ws; // 1 MiB: query bf16 [Nq][Lq][E]

  qconvert_kernel<<<dim3(NQ), dim3(256), 0, stream>>>(qry, qB);
  maxsim_kernel<<<dim3(ND / GDOCS, NQ / 8), dim3(256), 0, stream>>>(doc, qB, out);
}